// Round 6
// baseline (59.644 us; speedup 1.0000x reference)
//
#include <hip/hip_runtime.h>

// LengthRegulator: expand x[B,T,D] by integer durations into out[B,MAX_LEN,D],
// plus mel_len[B] = cumsum(duration)[:, -1].
// B=32, T=512, D=512, MAX_LEN=4096, durations in [0,10).
//
// R5: fused kernel, TPB=8 tokens/block (2048 blocks x 256 threads).
// Per block: wave-redundant in-register scan of the batch's 512 durations;
// since t0 is a multiple of 8, lane (t0>>3) holds cum[t0..t0+7] -> 8 shfl
// broadcasts + 1 for lo. Build a frame->token map (<=72 entries) in LDS,
// then write the block's CONTIGUOUS frame range [lo, hi): src rows are
// L1-resident (16 KB), stores are sequential. Zero region [mel, MAX_LEN)
// split into contiguous per-block chunks. One store-heavy loop per scan
// prologue (~50 store insts vs ~8 in R4).

typedef float f32x4 __attribute__((ext_vector_type(4)));
typedef int   i32x4 __attribute__((ext_vector_type(4)));

#define B_      32
#define T_      512
#define D_      512
#define MAXLEN_ 4096
#define TPB_    8                        // tokens per block
#define BPB_    (T_ / TPB_)              // blocks per batch = 64
#define NBLK_   (B_ * T_ / TPB_)         // 2048 blocks

__global__ void lr_fused_kernel(const float* __restrict__ x,
                                const int* __restrict__ dur,
                                float* __restrict__ out,
                                float* __restrict__ mel_out) {
    const int gid  = blockIdx.x;
    const int b    = gid >> 6;               // / BPB_
    const int blk  = gid & (BPB_ - 1);       // block within batch
    const int t0   = blk * TPB_;             // first token (multiple of 8)
    const int sub  = threadIdx.x >> 7;       // frame-parity group (0..1)
    const int fl   = threadIdx.x & 127;      // float4 index within row
    const int lane = threadIdx.x & 63;

    __shared__ int map[TPB_ * 9 + 8];        // frame -> token (<=72 used)

    // ---- wave-redundant inclusive scan of duration[b][:] in registers ----
    const i32x4* src = (const i32x4*)(dur + b * T_);
    i32x4 a = src[lane * 2];
    i32x4 c = src[lane * 2 + 1];
    int v0 = a.x,      v1 = v0 + a.y, v2 = v1 + a.z, v3 = v2 + a.w;
    int v4 = v3 + c.x, v5 = v4 + c.y, v6 = v5 + c.z, v7 = v6 + c.w;
    int s = v7;
    #pragma unroll
    for (int d = 1; d < 64; d <<= 1) {
        int u = __shfl_up(s, d, 64);
        if (lane >= d) s += u;
    }
    const int off = s - v7;                  // exclusive prefix of this lane
    v0 += off; v1 += off; v2 += off; v3 += off;
    v4 += off; v5 += off; v6 += off; v7 += off;
    // lane l holds cum[8l .. 8l+7]

    const int mel = __shfl(v7, 63, 64);
    const int L   = t0 >> 3;                 // lane holding cum[t0..t0+7]
    // boundaries e0..e8: e0 = cum[t0-1] (lo), e1..e8 = cum[t0..t0+7]
    int e0 = __shfl(v7, (L == 0) ? 0 : L - 1, 64);
    if (t0 == 0) e0 = 0;
    const int e1 = __shfl(v0, L, 64), e2 = __shfl(v1, L, 64);
    const int e3 = __shfl(v2, L, 64), e4 = __shfl(v3, L, 64);
    const int e5 = __shfl(v4, L, 64), e6 = __shfl(v5, L, 64);
    const int e7 = __shfl(v6, L, 64), e8 = __shfl(v7, L, 64);

    // ---- build frame->token map in LDS (threads 0..7, one token each) ----
    if (threadIdx.x < TPB_) {
        const int j = threadIdx.x;
        int ej = e0, ej1 = e1;
        ej  = (j == 1) ? e1 : ej;  ej1 = (j == 1) ? e2 : ej1;
        ej  = (j == 2) ? e2 : ej;  ej1 = (j == 2) ? e3 : ej1;
        ej  = (j == 3) ? e3 : ej;  ej1 = (j == 3) ? e4 : ej1;
        ej  = (j == 4) ? e4 : ej;  ej1 = (j == 4) ? e5 : ej1;
        ej  = (j == 5) ? e5 : ej;  ej1 = (j == 5) ? e6 : ej1;
        ej  = (j == 6) ? e6 : ej;  ej1 = (j == 6) ? e7 : ej1;
        ej  = (j == 7) ? e7 : ej;  ej1 = (j == 7) ? e8 : ej1;
        for (int f = ej; f < ej1; ++f) map[f - e0] = j;
    }
    __syncthreads();

    // ---- expand: contiguous frames [e0, min(e8, MAXLEN_)) ----
    const int nf = min(e8, MAXLEN_) - e0;
    const float* xblk = x + ((size_t)(b * T_ + t0)) * D_;
    float*       oblk = out + ((size_t)b * MAXLEN_ + e0) * D_;
    for (int fi = sub; fi < nf; fi += 2) {
        const int j = map[fi];
        const f32x4 v = ((const f32x4*)(xblk + (size_t)j * D_))[fl];
        __builtin_nontemporal_store(v, (f32x4*)(oblk + (size_t)fi * D_) + fl);
    }

    // ---- zero-fill: contiguous per-block chunk of [mel, MAXLEN_) ----
    const int nz    = (MAXLEN_ - mel > 0) ? (MAXLEN_ - mel) : 0;
    const int chunk = (nz + BPB_ - 1) >> 6;
    const int z0    = mel + blk * chunk;
    const int z1    = min(z0 + chunk, MAXLEN_);
    const f32x4 zv = {0.f, 0.f, 0.f, 0.f};
    for (int f = z0 + sub; f < z1; f += 2) {
        __builtin_nontemporal_store(
            zv, (f32x4*)(out + ((size_t)b * MAXLEN_ + f) * D_) + fl);
    }

    if (blk == 0 && threadIdx.x == 0) mel_out[b] = (float)mel;
}

extern "C" void kernel_launch(void* const* d_in, const int* in_sizes, int n_in,
                              void* d_out, int out_size, void* d_ws, size_t ws_size,
                              hipStream_t stream) {
    const float* x   = (const float*)d_in[0];
    const int*   dur = (const int*)d_in[1];
    // d_in[2] is max_len (=4096), compile-time constant here.

    float* out     = (float*)d_out;
    float* mel_out = out + (size_t)B_ * MAXLEN_ * D_;   // tail: 32 elements

    lr_fused_kernel<<<NBLK_, 256, 0, stream>>>(x, dur, out, mel_out);
}

// Round 7
// 55.403 us; speedup vs baseline: 1.0765x; 1.0765x over previous
//
#include <hip/hip_runtime.h>

// LengthRegulator: expand x[B,T,D] by integer durations into out[B,MAX_LEN,D],
// plus mel_len[B] = cumsum(duration)[:, -1].
// B=32, T=512, D=512, MAX_LEN=4096, durations in [0,10).
//
// R6: fused, ONE WAVE PER TOKEN (4 waves = 4 tokens per 256-thread block).
// Each wave holds its full source row in registers (2 x f32x4 per lane),
// loaded UNCONDITIONALLY at entry so the HBM read overlaps the in-register
// dur scan (R4 guarded the load behind the scan -> serialized latency).
// 2x store insts per scan vs R4 (wave owns whole row). No LDS, no map:
// register-pure store burst (R5's LDS-map indirection regressed).

typedef float f32x4 __attribute__((ext_vector_type(4)));
typedef int   i32x4 __attribute__((ext_vector_type(4)));

#define B_      32
#define T_      512
#define D_      512
#define MAXLEN_ 4096
#define BPB_    128                      // blocks per batch (4 tokens/block)
#define NBLK_   (B_ * BPB_)              // 4096 blocks

__global__ void lr_fused_kernel(const float* __restrict__ x,
                                const int* __restrict__ dur,
                                float* __restrict__ out,
                                float* __restrict__ mel_out) {
    const int gid  = blockIdx.x;
    const int b    = gid >> 7;               // / BPB_
    const int blk  = gid & (BPB_ - 1);
    const int wid  = threadIdx.x >> 6;       // wave id 0..3
    const int lane = threadIdx.x & 63;
    const int t    = blk * 4 + wid;          // wave-uniform token

    // ---- issue the row load FIRST (independent of the scan) ----
    const f32x4* row = (const f32x4*)(x + ((size_t)b * T_ + t) * D_);
    const f32x4 va = row[lane];
    const f32x4 vb = row[lane + 64];

    // ---- wave-redundant inclusive scan of duration[b][:] in registers ----
    const i32x4* src = (const i32x4*)(dur + b * T_);
    i32x4 a = src[lane * 2];
    i32x4 c = src[lane * 2 + 1];
    int v0 = a.x,      v1 = v0 + a.y, v2 = v1 + a.z, v3 = v2 + a.w;
    int v4 = v3 + c.x, v5 = v4 + c.y, v6 = v5 + c.z, v7 = v6 + c.w;
    int s = v7;
    #pragma unroll
    for (int d = 1; d < 64; d <<= 1) {
        int u = __shfl_up(s, d, 64);
        if (lane >= d) s += u;
    }
    const int off = s - v7;                  // exclusive prefix of this lane
    v0 += off; v1 += off; v2 += off; v3 += off;
    v4 += off; v5 += off; v6 += off; v7 += off;
    // lane l holds cum[8l .. 8l+7]

    const int mel = __shfl(v7, 63, 64);

    // ---- hi = cum[t], lo = cum[t-1] (t wave-uniform) ----
    const int e = t & 7;
    int sel = v0;
    sel = (e == 1) ? v1 : sel;  sel = (e == 2) ? v2 : sel;
    sel = (e == 3) ? v3 : sel;  sel = (e == 4) ? v4 : sel;
    sel = (e == 5) ? v5 : sel;  sel = (e == 6) ? v6 : sel;
    sel = (e == 7) ? v7 : sel;
    int hi = __shfl(sel, t >> 3, 64);
    int lo = 0;
    if (t > 0) {
        const int e2 = (t - 1) & 7;
        int sl = v0;
        sl = (e2 == 1) ? v1 : sl;  sl = (e2 == 2) ? v2 : sl;
        sl = (e2 == 3) ? v3 : sl;  sl = (e2 == 4) ? v4 : sl;
        sl = (e2 == 5) ? v5 : sl;  sl = (e2 == 6) ? v6 : sl;
        sl = (e2 == 7) ? v7 : sl;
        lo = __shfl(sl, (t - 1) >> 3, 64);
    }
    hi = min(hi, MAXLEN_);                   // robustness clamp
    lo = min(lo, MAXLEN_);

    // ---- expand: write the row to frames [lo, hi) ----
    f32x4* dst = (f32x4*)(out + ((size_t)b * MAXLEN_ + lo) * D_);
    for (int i = 0; i < hi - lo; ++i) {
        __builtin_nontemporal_store(va, dst + i * 128 + lane);
        __builtin_nontemporal_store(vb, dst + i * 128 + lane + 64);
    }

    // ---- zero-fill share: frames mel + t + 512k (exact disjoint cover) ----
    const f32x4 z = {0.f, 0.f, 0.f, 0.f};
    for (int f = mel + t; f < MAXLEN_; f += T_) {
        f32x4* dz = (f32x4*)(out + ((size_t)b * MAXLEN_ + f) * D_);
        __builtin_nontemporal_store(z, dz + lane);
        __builtin_nontemporal_store(z, dz + lane + 64);
    }

    if (blk == 0 && threadIdx.x == 0) mel_out[b] = (float)mel;
}

extern "C" void kernel_launch(void* const* d_in, const int* in_sizes, int n_in,
                              void* d_out, int out_size, void* d_ws, size_t ws_size,
                              hipStream_t stream) {
    const float* x   = (const float*)d_in[0];
    const int*   dur = (const int*)d_in[1];
    // d_in[2] is max_len (=4096), compile-time constant here.

    float* out     = (float*)d_out;
    float* mel_out = out + (size_t)B_ * MAXLEN_ * D_;   // tail: 32 elements

    lr_fused_kernel<<<NBLK_, 256, 0, stream>>>(x, dur, out, mel_out);
}